// Round 2
// baseline (27.723 us; speedup 1.0000x reference)
//
#include <hip/hip_runtime.h>
#include <cmath>

#define NATOMS 16384
#define MNBR   32
#define ROW    33      // center + 32 neighbors
#define NPAIR  496     // 32*31/2 triu pairs

__global__ __launch_bounds__(256) void sw_energy_kernel(
    const float* __restrict__ coords,
    const float* __restrict__ A_,    const float* __restrict__ B_,
    const float* __restrict__ p_,    const float* __restrict__ q_,
    const float* __restrict__ sigma_,const float* __restrict__ gamma_,
    const float* __restrict__ cutoff_,const float* __restrict__ lam_,
    const float* __restrict__ cb0_,  const float* __restrict__ cjk_,
    const int*   __restrict__ elements,
    const int*   __restrict__ nl,
    float* __restrict__ block_sums)
{
    __shared__ float sA[3], sB[3], sP[3], sQ[3], sS[3], sG[3], sC[3];
    __shared__ float sL[2], sCB[2], sCJK[2];
    __shared__ float ldx[4][32], ldy[4][32], ldz[4][32], lr[4][32], lh[4][32];
    __shared__ int   lpk[4][32];
    __shared__ float wsum[4];

    const int tid = threadIdx.x;
    if (tid < 3) {
        sA[tid] = A_[tid];    sB[tid] = B_[tid];
        sP[tid] = p_[tid];    sQ[tid] = q_[tid];
        sS[tid] = sigma_[tid];sG[tid] = gamma_[tid];
        sC[tid] = cutoff_[tid];
    }
    if (tid < 2) {
        sL[tid]   = lam_[tid];
        sCB[tid]  = cb0_[tid];
        sCJK[tid] = cjk_[tid];
    }
    __syncthreads();

    const int wave = tid >> 6;
    const int lane = tid & 63;
    const int atom = (blockIdx.x << 2) + wave;   // grid = NATOMS/4 -> always in range

    const int   base = atom * ROW;
    const int   ei   = elements[base];
    const int   ci   = nl[base];
    const float xix = coords[3*ci+0];
    const float xiy = coords[3*ci+1];
    const float xiz = coords[3*ci+2];

    float acc = 0.0f;

    // ---- stage neighbors + pair term (lanes 0..31, one neighbor each) ----
    if (lane < MNBR) {
        const int j  = nl[base + 1 + lane];
        const int ej = elements[base + 1 + lane];
        const float dx = coords[3*j+0] - xix;
        const float dy = coords[3*j+1] - xiy;
        const float dz = coords[3*j+2] - xiz;
        const float r  = sqrtf(dx*dx + dy*dy + dz*dz);
        const int   s  = ei + ej;
        const float c  = sC[s];
        const bool  valid = (r < c);
        float h = 0.0f;
        if (valid) {
            const float sg     = sS[s];
            const float inv_rc = 1.0f / (r - c);          // negative
            const float sr     = sg / r;                  // > 0
            const float l2     = log2f(sr);
            const float e2     = sA[s] * (sB[s]*exp2f(sP[s]*l2) - exp2f(sQ[s]*l2))
                               * expf(sg * inv_rc);
            acc += 0.5f * e2;
            h = sG[s] * inv_rc;                           // gamma/(r - c)
        }
        ldx[wave][lane] = dx;  ldy[wave][lane] = dy;  ldz[wave][lane] = dz;
        lr [wave][lane] = r;   lh [wave][lane] = h;
        lpk[wave][lane] = ej | (valid ? 2 : 0);
    }
    __syncthreads();

    // ---- triplet term: 496 (jj<kk) pairs, strided over 64 lanes ----
    for (int t = lane; t < NPAIR; t += 64) {
        // decode t -> (jj, kk) with t = kk*(kk-1)/2 + jj, jj < kk
        int kk = (int)(0.5f * (1.0f + sqrtf(8.0f*(float)t + 1.0f)));
        if (kk*(kk-1)/2 > t)            --kk;
        else if ((kk+1)*kk/2 <= t)      ++kk;
        const int jj = t - ((kk*(kk-1)) >> 1);

        const int pj = lpk[wave][jj];
        const int pk = lpk[wave][kk];
        const int ej = pj & 1;
        const int ek = pk & 1;
        if ((ei != ej) & (ej == ek) & ((pj & pk & 2) != 0)) {
            const float dxv  = ldx[wave][kk] - ldx[wave][jj];
            const float dyv  = ldy[wave][kk] - ldy[wave][jj];
            const float dzv  = ldz[wave][kk] - ldz[wave][jj];
            const float rjk2 = dxv*dxv + dyv*dyv + dzv*dzv;
            const int   s3   = ei + ej + ek;
            const int   ijk  = (s3 <= 1) ? 1 : 0;        // clip(2-s3, 0, 1)
            const float cjk  = sCJK[ijk];
            if (rjk2 < cjk*cjk) {
                const float rj   = lr[wave][jj];
                const float rk   = lr[wave][kk];
                const float cosb = (rj*rj + rk*rk - rjk2) * 0.5f / (rj * rk);
                const float dcb  = cosb - sCB[ijk];
                acc += sL[ijk] * expf(lh[wave][jj] + lh[wave][kk]) * dcb * dcb;
            }
        }
    }

    // ---- wave reduce (64 lanes) then block reduce ----
    #pragma unroll
    for (int off = 32; off > 0; off >>= 1)
        acc += __shfl_xor(acc, off, 64);
    if (lane == 0) wsum[wave] = acc;
    __syncthreads();
    if (tid == 0)
        block_sums[blockIdx.x] = wsum[0] + wsum[1] + wsum[2] + wsum[3];
}

__global__ __launch_bounds__(256) void sw_reduce_kernel(
    const float* __restrict__ in, float* __restrict__ out, int n)
{
    __shared__ float wsum[4];
    float acc = 0.0f;
    for (int i = threadIdx.x; i < n; i += 256) acc += in[i];
    #pragma unroll
    for (int off = 32; off > 0; off >>= 1)
        acc += __shfl_xor(acc, off, 64);
    if ((threadIdx.x & 63) == 0) wsum[threadIdx.x >> 6] = acc;
    __syncthreads();
    if (threadIdx.x == 0) out[0] = wsum[0] + wsum[1] + wsum[2] + wsum[3];
}

extern "C" void kernel_launch(void* const* d_in, const int* in_sizes, int n_in,
                              void* d_out, int out_size, void* d_ws, size_t ws_size,
                              hipStream_t stream)
{
    const float* coords  = (const float*)d_in[0];
    const float* A_      = (const float*)d_in[1];
    const float* B_      = (const float*)d_in[2];
    const float* p_      = (const float*)d_in[3];
    const float* q_      = (const float*)d_in[4];
    const float* sigma_  = (const float*)d_in[5];
    const float* gamma_  = (const float*)d_in[6];
    const float* cutoff_ = (const float*)d_in[7];
    const float* lam_    = (const float*)d_in[8];
    const float* cb0_    = (const float*)d_in[9];
    const float* cjk_    = (const float*)d_in[10];
    const int*   elements= (const int*)d_in[11];
    const int*   nl      = (const int*)d_in[12];

    float* out   = (float*)d_out;
    float* bsums = (float*)d_ws;               // 4096 floats scratch

    const int nblocks = NATOMS / 4;            // one wave per atom, 4 waves/block
    sw_energy_kernel<<<nblocks, 256, 0, stream>>>(
        coords, A_, B_, p_, q_, sigma_, gamma_, cutoff_,
        lam_, cb0_, cjk_, elements, nl, bsums);
    sw_reduce_kernel<<<1, 256, 0, stream>>>(bsums, out, nblocks);
}

// Round 3
// 13.381 us; speedup vs baseline: 2.0718x; 2.0718x over previous
//
#include <hip/hip_runtime.h>
#include <cmath>

#define NATOMS 16384
#define MNBR   32
#define ROW    33      // center + 32 neighbors
#define APB    8       // atoms per block (4 waves x 2 half-waves)

__device__ __forceinline__ float sel3(int s, float v0, float v1, float v2) {
    float r = (s == 0) ? v0 : v1;
    return (s == 2) ? v2 : r;
}

__global__ __launch_bounds__(256) void sw_energy_kernel(
    const float* __restrict__ coords,
    const float* __restrict__ A_,    const float* __restrict__ B_,
    const float* __restrict__ p_,    const float* __restrict__ q_,
    const float* __restrict__ sigma_,const float* __restrict__ gamma_,
    const float* __restrict__ cutoff_,const float* __restrict__ lam_,
    const float* __restrict__ cb0_,  const float* __restrict__ cjk_,
    const int*   __restrict__ elements,
    const int*   __restrict__ nl,
    float* __restrict__ block_sums)
{
    // wave-private compacted triplet candidates: [wave][side][slot]
    __shared__ float cdx[4][2][32], cdy[4][2][32], cdz[4][2][32];
    __shared__ float crr[4][2][32], chh[4][2][32];
    __shared__ float wsum[4];

    const int tid  = threadIdx.x;
    const int wave = tid >> 6;
    const int lane = tid & 63;
    const int side = lane >> 5;
    const int hl   = lane & 31;

    // uniform params -> scalar loads, no LDS, no barrier
    const float a0 = A_[0],     a1 = A_[1],     a2 = A_[2];
    const float b0 = B_[0],     b1 = B_[1],     b2 = B_[2];
    const float p0 = p_[0],     p1 = p_[1],     p2 = p_[2];
    const float q0 = q_[0],     q1 = q_[1],     q2 = q_[2];
    const float s0 = sigma_[0], s1 = sigma_[1], s2v = sigma_[2];
    const float g0 = gamma_[0], g1 = gamma_[1], g2 = gamma_[2];
    const float c0 = cutoff_[0],c1 = cutoff_[1],c2 = cutoff_[2];
    const float lam0 = lam_[0], lam1 = lam_[1];
    const float cb0v = cb0_[0], cb1v = cb0_[1];
    const float cjk0 = cjk_[0], cjk1 = cjk_[1];

    const int atom = blockIdx.x * APB + wave * 2 + side;   // grid exact
    const int base = atom * ROW;

    const int   ei  = elements[base];
    const int   ci  = nl[base];
    const float xix = coords[3*ci+0];
    const float xiy = coords[3*ci+1];
    const float xiz = coords[3*ci+2];

    float acc = 0.0f;

    // ---- pair term + triplet-candidate compaction (all 64 lanes busy) ----
    const int   j  = nl[base + 1 + hl];
    const int   ej = elements[base + 1 + hl];
    const float dx = coords[3*j+0] - xix;
    const float dy = coords[3*j+1] - xiy;
    const float dz = coords[3*j+2] - xiz;
    const float r  = sqrtf(dx*dx + dy*dy + dz*dz);
    const int   s  = ei + ej;
    const float c  = sel3(s, c0, c1, c2);
    const bool  valid = (r < c);

    float h = 0.0f;
    if (valid) {
        const float sg     = sel3(s, s0, s1, s2v);
        const float inv_rc = 1.0f / (r - c);               // negative
        const float l2     = log2f(sg / r);
        const float e2     = sel3(s, a0, a1, a2)
                           * (sel3(s, b0, b1, b2) * exp2f(sel3(s, p0, p1, p2) * l2)
                              - exp2f(sel3(s, q0, q1, q2) * l2))
                           * expf(sg * inv_rc);
        acc += 0.5f * e2;
        h = sel3(s, g0, g1, g2) * inv_rc;                  // gamma/(r - c); s==1 for triplet members
    }

    // triplet participation: ej == 1-ei (=> ej==ek and ei!=ej automatically) and rij<cij
    const bool participate = valid && (ej != ei);
    const unsigned long long ballot   = __ballot(participate);
    const unsigned long long halfmask = side ? 0xFFFFFFFF00000000ull : 0x00000000FFFFFFFFull;
    const int m = __popcll(ballot & halfmask);
    if (participate) {
        const int slot = __popcll(ballot & halfmask & ((1ull << lane) - 1ull));
        cdx[wave][side][slot] = dx;
        cdy[wave][side][slot] = dy;
        cdz[wave][side][slot] = dz;
        crr[wave][side][slot] = r;
        chh[wave][side][slot] = h;
    }
    // wave-private LDS, wave-lockstep: no barrier needed

    // ---- triplet term over compacted pairs (usually <= 1 iteration) ----
    const float lam_e = ei ? lam1 : lam0;
    const float cb_e  = ei ? cb1v : cb0v;
    const float cjk_e = ei ? cjk1 : cjk0;
    const float cjk2  = cjk_e * cjk_e;
    const int npairs  = (m * (m - 1)) >> 1;

    for (int t = hl; t < npairs; t += 32) {
        int kk = (int)(0.5f * (1.0f + sqrtf(8.0f * (float)t + 1.0f)));
        if (kk*(kk-1)/2 > t)          --kk;
        else if ((kk+1)*kk/2 <= t)    ++kk;
        const int jj = t - ((kk*(kk-1)) >> 1);

        const float dxv  = cdx[wave][side][kk] - cdx[wave][side][jj];
        const float dyv  = cdy[wave][side][kk] - cdy[wave][side][jj];
        const float dzv  = cdz[wave][side][kk] - cdz[wave][side][jj];
        const float rjk2 = dxv*dxv + dyv*dyv + dzv*dzv;
        if (rjk2 < cjk2) {
            const float rj   = crr[wave][side][jj];
            const float rk   = crr[wave][side][kk];
            const float cosb = (rj*rj + rk*rk - rjk2) * 0.5f / (rj * rk);
            const float dcb  = cosb - cb_e;
            acc += lam_e * expf(chh[wave][side][jj] + chh[wave][side][kk]) * dcb * dcb;
        }
    }

    // ---- wave reduce (64 lanes, covers both half-waves) then block reduce ----
    #pragma unroll
    for (int off = 32; off > 0; off >>= 1)
        acc += __shfl_xor(acc, off, 64);
    if (lane == 0) wsum[wave] = acc;
    __syncthreads();
    if (tid == 0)
        block_sums[blockIdx.x] = wsum[0] + wsum[1] + wsum[2] + wsum[3];
}

__global__ __launch_bounds__(256) void sw_reduce_kernel(
    const float* __restrict__ in, float* __restrict__ out, int n)
{
    __shared__ float wsum[4];
    float acc = 0.0f;
    for (int i = threadIdx.x; i < n; i += 256) acc += in[i];
    #pragma unroll
    for (int off = 32; off > 0; off >>= 1)
        acc += __shfl_xor(acc, off, 64);
    if ((threadIdx.x & 63) == 0) wsum[threadIdx.x >> 6] = acc;
    __syncthreads();
    if (threadIdx.x == 0) out[0] = wsum[0] + wsum[1] + wsum[2] + wsum[3];
}

extern "C" void kernel_launch(void* const* d_in, const int* in_sizes, int n_in,
                              void* d_out, int out_size, void* d_ws, size_t ws_size,
                              hipStream_t stream)
{
    const float* coords  = (const float*)d_in[0];
    const float* A_      = (const float*)d_in[1];
    const float* B_      = (const float*)d_in[2];
    const float* p_      = (const float*)d_in[3];
    const float* q_      = (const float*)d_in[4];
    const float* sigma_  = (const float*)d_in[5];
    const float* gamma_  = (const float*)d_in[6];
    const float* cutoff_ = (const float*)d_in[7];
    const float* lam_    = (const float*)d_in[8];
    const float* cb0_    = (const float*)d_in[9];
    const float* cjk_    = (const float*)d_in[10];
    const int*   elements= (const int*)d_in[11];
    const int*   nl      = (const int*)d_in[12];

    float* out   = (float*)d_out;
    float* bsums = (float*)d_ws;               // 2048 floats scratch

    const int nblocks = NATOMS / APB;          // 2048
    sw_energy_kernel<<<nblocks, 256, 0, stream>>>(
        coords, A_, B_, p_, q_, sigma_, gamma_, cutoff_,
        lam_, cb0_, cjk_, elements, nl, bsums);
    sw_reduce_kernel<<<1, 256, 0, stream>>>(bsums, out, nblocks);
}